// Round 6
// baseline (132.829 us; speedup 1.0000x reference)
//
#include <hip/hip_runtime.h>
#include <math.h>

// Problem shape (fixed by setup_inputs)
constexpr int B = 16, H = 384, W = 1280;
constexpr int HW = H * W;
constexpr int NPIX = B * HW;             // 7,864,320
constexpr int HW8 = HW / 8;              // 61,440 8-pixel granules per batch image
constexpr int W8 = W / 8;                // 160
constexpr int NBLOCKS = 2048;
constexpr int NTHREADS = 256;
constexpr int NXCD = 8;
constexpr int BLK_PER_XCD = NBLOCKS / NXCD;            // 256
constexpr int THR_PER_XCD = BLK_PER_XCD * NTHREADS;    // 65536
constexpr float EPSV = 1e-8f;

// ws float layout: [0,384) per-batch params (24 floats each); [384,384+NBLOCKS) block partials
constexpr int PARAMS_FLOATS = B * 24;

__device__ inline void aa_to_R(float x, float y, float z, float R[9]) {
    float t2 = x * x + y * y + z * z;
    float th = sqrtf(t2 + 1e-12f);
    float A = sinf(th) / th;
    float Bc = (1.0f - cosf(th)) / (t2 + 1e-12f);
    R[0] = 1.0f + Bc * (-(y * y + z * z));
    R[1] = A * (-z) + Bc * (x * y);
    R[2] = A * ( y) + Bc * (x * z);
    R[3] = A * ( z) + Bc * (x * y);
    R[4] = 1.0f + Bc * (-(x * x + z * z));
    R[5] = A * (-x) + Bc * (y * z);
    R[6] = A * (-y) + Bc * (x * z);
    R[7] = A * ( x) + Bc * (y * z);
    R[8] = 1.0f + Bc * (-(x * x + y * y));
}

__device__ inline void mat3_mul(const float* A, const float* Bm, float* C) {
#pragma unroll
    for (int i = 0; i < 3; i++)
#pragma unroll
        for (int j = 0; j < 3; j++)
            C[i * 3 + j] = A[i * 3 + 0] * Bm[0 * 3 + j]
                         + A[i * 3 + 1] * Bm[1 * 3 + j]
                         + A[i * 3 + 2] * Bm[2 * 3 + j];
}

__device__ inline void compute_dir(const float Ra[9], const float Rb[9],
                                   const float ta[3], const float tb[3],
                                   const float K[9], const float Ki[9],
                                   float* out) {
    float Rrel[9];
#pragma unroll
    for (int i = 0; i < 3; i++)
#pragma unroll
        for (int j = 0; j < 3; j++)
            Rrel[i * 3 + j] = Ra[0 * 3 + i] * Rb[0 * 3 + j]
                            + Ra[1 * 3 + i] * Rb[1 * 3 + j]
                            + Ra[2 * 3 + i] * Rb[2 * 3 + j];
    float dt[3] = { tb[0] - ta[0], tb[1] - ta[1], tb[2] - ta[2] };
    float trel[3];
#pragma unroll
    for (int i = 0; i < 3; i++)
        trel[i] = Ra[0 * 3 + i] * dt[0] + Ra[1 * 3 + i] * dt[1] + Ra[2 * 3 + i] * dt[2];
    float tmp[9], M[9];
    mat3_mul(Rrel, Ki, tmp);
    mat3_mul(K, tmp, M);
#pragma unroll
    for (int i = 0; i < 9; i++) out[i] = M[i];
#pragma unroll
    for (int i = 0; i < 3; i++)
        out[9 + i] = K[i * 3 + 0] * trel[0] + K[i * 3 + 1] * trel[1] + K[i * 3 + 2] * trel[2];
}

__global__ void grl_setup_kernel(const float* __restrict__ cpos, const float* __restrict__ npos,
                                 const float* __restrict__ cang, const float* __restrict__ nang,
                                 const float* __restrict__ Kmat, float* __restrict__ ws) {
    int b = threadIdx.x;
    if (b >= B) return;
    float Rc[9], Rn[9];
    aa_to_R(cang[3 * b + 0], cang[3 * b + 1], cang[3 * b + 2], Rc);
    aa_to_R(nang[3 * b + 0], nang[3 * b + 1], nang[3 * b + 2], Rn);
    float tc[3] = { cpos[3 * b + 0], cpos[3 * b + 1], cpos[3 * b + 2] };
    float tn[3] = { npos[3 * b + 0], npos[3 * b + 1], npos[3 * b + 2] };
    float K[9];
#pragma unroll
    for (int i = 0; i < 9; i++) K[i] = Kmat[i];
    float det = K[0] * (K[4] * K[8] - K[5] * K[7])
              - K[1] * (K[3] * K[8] - K[5] * K[6])
              + K[2] * (K[3] * K[7] - K[4] * K[6]);
    float id = 1.0f / det;
    float Ki[9] = {
        (K[4] * K[8] - K[5] * K[7]) * id, (K[2] * K[7] - K[1] * K[8]) * id, (K[1] * K[5] - K[2] * K[4]) * id,
        (K[5] * K[6] - K[3] * K[8]) * id, (K[0] * K[8] - K[2] * K[6]) * id, (K[2] * K[3] - K[0] * K[5]) * id,
        (K[3] * K[7] - K[4] * K[6]) * id, (K[1] * K[6] - K[0] * K[7]) * id, (K[0] * K[4] - K[1] * K[3]) * id };
    float* out = ws + b * 24;
    compute_dir(Rc, Rn, tc, tn, K, Ki, out);        // dir0: T_n2c
    compute_dir(Rn, Rc, tn, tc, K, Ki, out + 12);   // dir1: T_c2n
}

// 8-byte pair load at 4B alignment (legal lowering chosen by compiler).
__device__ inline float2 load2u(const float* __restrict__ p) {
    float2 v;
    __builtin_memcpy(&v, p, sizeof(float2));
    return v;
}

// R1: batch<->XCD pinning (3.9 MB/batch fits one XCD's 4 MiB L2).
// R4: clustered pair-loads + sched_barrier (worked: VGPR 44->64, -32%).
// R6: widen granule to 8 px/thread -> 32 pair-gathers per cluster (2x R4
//     in-flight) WITHOUT cutting occupancy (R5 lesson: perf ~ waves x MLP).
//     Folded bilinear coefficients (5 floats/tap) keep stage state ~150 VGPR;
//     launch_bounds(256,3) caps at ~170.
__global__ __launch_bounds__(NTHREADS, 3) void grl_warp_loss_kernel(
        const float* __restrict__ cur, const float* __restrict__ nxt,
        const float* __restrict__ ws, float* __restrict__ partials) {
    int bid = blockIdx.x;
    int xcd = bid & (NXCD - 1);
    int j   = bid >> 3;
    int tid0 = j * NTHREADS + (int)threadIdx.x;   // 0..65535
    float sum = 0.0f;

    for (int bb = 0; bb < 2; ++bb) {
        int b = xcd * 2 + bb;
        const float* __restrict__ prm = ws + b * 24;
        float M[2][9], kt[2][3];
#pragma unroll
        for (int i = 0; i < 9; i++) { M[0][i] = prm[i]; M[1][i] = prm[12 + i]; }
#pragma unroll
        for (int i = 0; i < 3; i++) { kt[0][i] = prm[9 + i]; kt[1][i] = prm[21 + i]; }
        const float* __restrict__ srcimg[2];
        srcimg[0] = cur + b * HW;   // dir0 samples cur
        srcimg[1] = nxt + b * HW;   // dir1 samples nxt

        for (int idx = tid0; idx < HW8; idx += THR_PER_XCD) {
            int h  = idx / W8;
            int w8 = idx - h * W8;
            int p  = idx * 8;
            const float4 c4a = *(const float4*)(srcimg[0] + p);
            const float4 c4b = *(const float4*)(srcimg[0] + p + 4);
            const float4 n4a = *(const float4*)(srcimg[1] + p);
            const float4 n4b = *(const float4*)(srcimg[1] + p + 4);
            float fh = (float)h;
            // dir0 warps with dst depth = next; dir1 with dst depth = current
            float dst[2][8] = { { n4a.x, n4a.y, n4a.z, n4a.w, n4b.x, n4b.y, n4b.z, n4b.w },
                                { c4a.x, c4a.y, c4a.z, c4a.w, c4b.x, c4b.y, c4b.z, c4b.w } };

            float2 pv0[2][8], pv1[2][8];          // pair values rows y0/y1
            float  c00[2][8], c01[2][8], c10[2][8], c11[2][8];

#pragma unroll
            for (int dir = 0; dir < 2; dir++) {
                float rx = M[dir][1] * fh + M[dir][2];
                float ry = M[dir][4] * fh + M[dir][5];
                float rz = M[dir][7] * fh + M[dir][8];
#pragma unroll
                for (int k = 0; k < 8; k++) {
                    float fw = (float)(w8 * 8 + k);
                    float d  = dst[dir][k];
                    float px = d * (M[dir][0] * fw + rx) + kt[dir][0];
                    float py = d * (M[dir][3] * fw + ry) + kt[dir][1];
                    float pz = d * (M[dir][6] * fw + rz) + kt[dir][2];
                    float scale = (fabsf(pz) > EPSV) ? (1.0f / pz) : 1.0f;
                    float ix = px * scale, iy = py * scale;
                    float x0f = floorf(ix), y0f = floorf(iy);
                    float wx1 = ix - x0f, wy1 = iy - y0f;
                    float wx0 = 1.0f - wx1, wy0 = 1.0f - wy1;
                    // validity on UNclamped tap coords (matches reference zero-pad)
                    bool vx0 = (x0f >= 0.0f)        & (x0f <= (float)(W - 1));
                    bool vx1 = (x0f + 1.0f >= 0.0f) & (x0f + 1.0f <= (float)(W - 1));
                    bool vy0 = (y0f >= 0.0f)        & (y0f <= (float)(H - 1));
                    bool vy1 = (y0f + 1.0f >= 0.0f) & (y0f + 1.0f <= (float)(H - 1));
                    float mxl = vx0 ? wx0 : 0.0f;
                    float mxr = vx1 ? wx1 : 0.0f;
                    float myt = vy0 ? wy0 : 0.0f;
                    float myb = vy1 ? wy1 : 0.0f;
                    int xi0 = (int)fminf(fmaxf(x0f,        0.0f), (float)(W - 1));
                    int xi1 = (int)fminf(fmaxf(x0f + 1.0f, 0.0f), (float)(W - 1));
                    int yi0 = (int)fminf(fmaxf(y0f,        0.0f), (float)(H - 1));
                    int yi1 = (int)fminf(fmaxf(y0f + 1.0f, 0.0f), (float)(H - 1));
                    int xp  = min(xi0, W - 2);        // pair base, always in-bounds
                    int sL = xi0 - xp, sR = xi1 - xp; // 0/1 selects within pair
                    float ax = (sL ? 0.0f : mxl) + (sR ? 0.0f : mxr);   // weight on p.x
                    float bx = (sL ? mxl : 0.0f) + (sR ? mxr : 0.0f);   // weight on p.y
                    c00[dir][k] = ax * myt;
                    c01[dir][k] = bx * myt;
                    c10[dir][k] = ax * myb;
                    c11[dir][k] = bx * myb;
                    pv0[dir][k] = load2u(srcimg[dir] + yi0 * W + xp);
                    pv1[dir][k] = load2u(srcimg[dir] + yi1 * W + xp);
                }
            }
            // All 32 pair-loads in flight; no sinking past this point.
            __builtin_amdgcn_sched_barrier(0);
#pragma unroll
            for (int dir = 0; dir < 2; dir++)
#pragma unroll
                for (int k = 0; k < 8; k++) {
                    float g = pv0[dir][k].x * c00[dir][k] + pv0[dir][k].y * c01[dir][k]
                            + pv1[dir][k].x * c10[dir][k] + pv1[dir][k].y * c11[dir][k];
                    sum += fabsf(g - dst[dir][k]);
                }
        }
    }

#pragma unroll
    for (int off2 = 32; off2 > 0; off2 >>= 1) sum += __shfl_down(sum, off2, 64);
    __shared__ float smem[NTHREADS / 64];
    int lane = threadIdx.x & 63, wid = threadIdx.x >> 6;
    if (lane == 0) smem[wid] = sum;
    __syncthreads();
    if (threadIdx.x == 0) {
        float t = 0.0f;
#pragma unroll
        for (int i = 0; i < NTHREADS / 64; i++) t += smem[i];
        partials[blockIdx.x] = t;
    }
}

__global__ __launch_bounds__(256) void grl_finalize_kernel(const float* __restrict__ partials,
                                                           float* __restrict__ out) {
    float sum = 0.0f;
    for (int i = threadIdx.x; i < NBLOCKS; i += 256) sum += partials[i];
#pragma unroll
    for (int off = 32; off > 0; off >>= 1) sum += __shfl_down(sum, off, 64);
    __shared__ float smem[4];
    int lane = threadIdx.x & 63, wid = threadIdx.x >> 6;
    if (lane == 0) smem[wid] = sum;
    __syncthreads();
    if (threadIdx.x == 0) {
        float t = smem[0] + smem[1] + smem[2] + smem[3];
        out[0] = t * (0.1f / (2.0f * (float)NPIX));
    }
}

extern "C" void kernel_launch(void* const* d_in, const int* in_sizes, int n_in,
                              void* d_out, int out_size, void* d_ws, size_t ws_size,
                              hipStream_t stream) {
    const float* cur  = (const float*)d_in[0];
    const float* nxt  = (const float*)d_in[1];
    const float* cpos = (const float*)d_in[2];
    const float* npos = (const float*)d_in[3];
    const float* cang = (const float*)d_in[4];
    const float* nang = (const float*)d_in[5];
    const float* Kmat = (const float*)d_in[6];
    float* ws = (float*)d_ws;
    float* partials = ws + PARAMS_FLOATS;

    grl_setup_kernel<<<1, 64, 0, stream>>>(cpos, npos, cang, nang, Kmat, ws);
    grl_warp_loss_kernel<<<NBLOCKS, NTHREADS, 0, stream>>>(cur, nxt, ws, partials);
    grl_finalize_kernel<<<1, 256, 0, stream>>>(partials, (float*)d_out);
}

// Round 7
// 97.276 us; speedup vs baseline: 1.3655x; 1.3655x over previous
//
#include <hip/hip_runtime.h>
#include <hip/hip_fp16.h>
#include <math.h>

// Problem shape (fixed by setup_inputs)
constexpr int B = 16, H = 384, W = 1280;
constexpr int HW = H * W;                // 491,520
constexpr int NPIX = B * HW;             // 7,864,320
constexpr int HW4 = HW / 4;              // 122,880 4-px granules per image
constexpr int W4 = W / 4;                // 320
constexpr int NBLOCKS = 2048;
constexpr int NTHREADS = 256;
constexpr int NXCD = 8;
constexpr int BLK_PER_XCD = NBLOCKS / NXCD;            // 256
constexpr int THR_PER_XCD = BLK_PER_XCD * NTHREADS;    // 65536
constexpr float EPSV = 1e-8f;

// ws layout (floats): [0,384) params; [384,2432) block partials; packed @ 4096
constexpr int PARAMS_FLOATS = B * 24;
constexpr int PACK_OFF_FLOATS = 4096;                  // 16 KB aligned
constexpr size_t PACKED_BYTES = (size_t)B * 2 * HW * 4;     // 62,914,560
constexpr size_t WS_NEEDED = (size_t)PACK_OFF_FLOATS * 4 + PACKED_BYTES;

typedef float f32x4 __attribute__((ext_vector_type(4)));

__device__ inline void aa_to_R(float x, float y, float z, float R[9]) {
    float t2 = x * x + y * y + z * z;
    float th = sqrtf(t2 + 1e-12f);
    float A = sinf(th) / th;
    float Bc = (1.0f - cosf(th)) / (t2 + 1e-12f);
    R[0] = 1.0f + Bc * (-(y * y + z * z));
    R[1] = A * (-z) + Bc * (x * y);
    R[2] = A * ( y) + Bc * (x * z);
    R[3] = A * ( z) + Bc * (x * y);
    R[4] = 1.0f + Bc * (-(x * x + z * z));
    R[5] = A * (-x) + Bc * (y * z);
    R[6] = A * (-y) + Bc * (x * z);
    R[7] = A * ( x) + Bc * (y * z);
    R[8] = 1.0f + Bc * (-(x * x + y * y));
}

__device__ inline void mat3_mul(const float* A, const float* Bm, float* C) {
#pragma unroll
    for (int i = 0; i < 3; i++)
#pragma unroll
        for (int j = 0; j < 3; j++)
            C[i * 3 + j] = A[i * 3 + 0] * Bm[0 * 3 + j]
                         + A[i * 3 + 1] * Bm[1 * 3 + j]
                         + A[i * 3 + 2] * Bm[2 * 3 + j];
}

__device__ inline void compute_dir(const float Ra[9], const float Rb[9],
                                   const float ta[3], const float tb[3],
                                   const float K[9], const float Ki[9],
                                   float* out) {
    float Rrel[9];
#pragma unroll
    for (int i = 0; i < 3; i++)
#pragma unroll
        for (int j = 0; j < 3; j++)
            Rrel[i * 3 + j] = Ra[0 * 3 + i] * Rb[0 * 3 + j]
                            + Ra[1 * 3 + i] * Rb[1 * 3 + j]
                            + Ra[2 * 3 + i] * Rb[2 * 3 + j];
    float dt[3] = { tb[0] - ta[0], tb[1] - ta[1], tb[2] - ta[2] };
    float trel[3];
#pragma unroll
    for (int i = 0; i < 3; i++)
        trel[i] = Ra[0 * 3 + i] * dt[0] + Ra[1 * 3 + i] * dt[1] + Ra[2 * 3 + i] * dt[2];
    float tmp[9], M[9];
    mat3_mul(Rrel, Ki, tmp);
    mat3_mul(K, tmp, M);
#pragma unroll
    for (int i = 0; i < 9; i++) out[i] = M[i];
#pragma unroll
    for (int i = 0; i < 3; i++)
        out[9 + i] = K[i * 3 + 0] * trel[0] + K[i * 3 + 1] * trel[1] + K[i * 3 + 2] * trel[2];
}

__global__ void grl_setup_kernel(const float* __restrict__ cpos, const float* __restrict__ npos,
                                 const float* __restrict__ cang, const float* __restrict__ nang,
                                 const float* __restrict__ Kmat, float* __restrict__ ws) {
    int b = threadIdx.x;
    if (b >= B) return;
    float Rc[9], Rn[9];
    aa_to_R(cang[3 * b + 0], cang[3 * b + 1], cang[3 * b + 2], Rc);
    aa_to_R(nang[3 * b + 0], nang[3 * b + 1], nang[3 * b + 2], Rn);
    float tc[3] = { cpos[3 * b + 0], cpos[3 * b + 1], cpos[3 * b + 2] };
    float tn[3] = { npos[3 * b + 0], npos[3 * b + 1], npos[3 * b + 2] };
    float K[9];
#pragma unroll
    for (int i = 0; i < 9; i++) K[i] = Kmat[i];
    float det = K[0] * (K[4] * K[8] - K[5] * K[7])
              - K[1] * (K[3] * K[8] - K[5] * K[6])
              + K[2] * (K[3] * K[7] - K[4] * K[6]);
    float id = 1.0f / det;
    float Ki[9] = {
        (K[4] * K[8] - K[5] * K[7]) * id, (K[2] * K[7] - K[1] * K[8]) * id, (K[1] * K[5] - K[2] * K[4]) * id,
        (K[5] * K[6] - K[3] * K[8]) * id, (K[0] * K[8] - K[2] * K[6]) * id, (K[2] * K[3] - K[0] * K[5]) * id,
        (K[3] * K[7] - K[4] * K[6]) * id, (K[1] * K[6] - K[0] * K[7]) * id, (K[0] * K[4] - K[1] * K[3]) * id };
    float* out = ws + b * 24;
    compute_dir(Rc, Rn, tc, tn, K, Ki, out);        // dir0: T_n2c (dst=next, src=cur)
    compute_dir(Rn, Rc, tn, tc, K, Ki, out + 12);   // dir1: T_c2n (dst=cur, src=nxt)
}

// ---- Pack pre-pass: packed[y][x] = half2(v[y][x], v[min(y+1,H-1)][x]) ----
// One 8B load in the warp kernel then covers all 4 bilinear taps.
// XCD-pinned identically to the warp kernel (batch 2x,2x+1 on XCD x).
constexpr int PK_GRAN_PER_BATCH = 2 * HW4;             // 245,760 (2 images)
constexpr int PK_BLOCKS = (B * 2 * HW4) / NTHREADS;    // 15,360

__global__ __launch_bounds__(NTHREADS) void grl_pack_kernel(
        const float* __restrict__ cur, const float* __restrict__ nxt,
        unsigned int* __restrict__ packed) {
    int bid = blockIdx.x;
    int xcd = bid & (NXCD - 1);
    int j   = bid >> 3;                                // 0..1919
    int g   = j * NTHREADS + (int)threadIdx.x;         // 0..491,519
    int bb  = g / PK_GRAN_PER_BATCH;                   // 0/1
    int r   = g - bb * PK_GRAN_PER_BATCH;
    int img = r / HW4;                                 // 0=cur, 1=nxt
    int rr  = r - img * HW4;
    int y   = rr / W4;
    int xg  = rr - y * W4;
    int x0  = xg * 4;
    int b   = xcd * 2 + bb;
    const float* __restrict__ src = (img ? nxt : cur) + (size_t)b * HW;
    int y1 = min(y + 1, H - 1);
    const float4 v0 = *(const float4*)(src + y  * W + x0);
    const float4 v1 = *(const float4*)(src + y1 * W + x0);
    __half2 h0 = __halves2half2(__float2half_rn(v0.x), __float2half_rn(v1.x));
    __half2 h1 = __halves2half2(__float2half_rn(v0.y), __float2half_rn(v1.y));
    __half2 h2 = __halves2half2(__float2half_rn(v0.z), __float2half_rn(v1.z));
    __half2 h3 = __halves2half2(__float2half_rn(v0.w), __float2half_rn(v1.w));
    uint4 o;
    __builtin_memcpy(&o.x, &h0, 4);
    __builtin_memcpy(&o.y, &h1, 4);
    __builtin_memcpy(&o.z, &h2, 4);
    __builtin_memcpy(&o.w, &h3, 4);
    *(uint4*)(packed + (size_t)(b * 2 + img) * HW + y * W + x0) = o;
}

__device__ inline uint2 load8u(const unsigned int* __restrict__ p) {
    uint2 v;
    __builtin_memcpy(&v, p, sizeof(uint2));
    return v;
}
__device__ inline float2 h2f2(unsigned int w) {
    __half2 h;
    __builtin_memcpy(&h, &w, 4);
    return __half22float2(h);   // .x = lo (row y), .y = hi (row y+1)
}

// ---- Fast warp kernel: one 8B packed load per (pixel, dir) ----
__global__ __launch_bounds__(NTHREADS, 4) void grl_warp_loss_packed(
        const float* __restrict__ cur, const float* __restrict__ nxt,
        const unsigned int* __restrict__ packed,
        const float* __restrict__ ws, float* __restrict__ partials) {
    int bid = blockIdx.x;
    int xcd = bid & (NXCD - 1);
    int j   = bid >> 3;
    int tid0 = j * NTHREADS + (int)threadIdx.x;
    float sum = 0.0f;

    for (int bb = 0; bb < 2; ++bb) {
        int b = xcd * 2 + bb;
        const float* __restrict__ prm = ws + b * 24;
        float M[2][9], kt[2][3];
#pragma unroll
        for (int i = 0; i < 9; i++) { M[0][i] = prm[i]; M[1][i] = prm[12 + i]; }
#pragma unroll
        for (int i = 0; i < 3; i++) { kt[0][i] = prm[9 + i]; kt[1][i] = prm[21 + i]; }
        const unsigned int* __restrict__ pk[2] = {
            packed + (size_t)(b * 2 + 0) * HW,     // dir0 gathers cur
            packed + (size_t)(b * 2 + 1) * HW };   // dir1 gathers nxt
        const float* __restrict__ curb = cur + (size_t)b * HW;
        const float* __restrict__ nxtb = nxt + (size_t)b * HW;

        for (int idx = tid0; idx < HW4; idx += THR_PER_XCD) {
            int h  = idx / W4;
            int w4 = idx - h * W4;
            int p  = idx * 4;
            // exact f32 dst depths, nontemporal (protect L2's packed working set)
            f32x4 c4 = __builtin_nontemporal_load((const f32x4*)(curb + p));
            f32x4 n4 = __builtin_nontemporal_load((const f32x4*)(nxtb + p));
            float fh = (float)h;
            float dst[2][4] = { { n4.x, n4.y, n4.z, n4.w },
                                { c4.x, c4.y, c4.z, c4.w } };

            uint2  pv[2][4];
            float  cax[2][4], cbx[2][4], cra[2][4], crb[2][4];

#pragma unroll
            for (int dir = 0; dir < 2; dir++) {
                float rx = M[dir][1] * fh + M[dir][2];
                float ry = M[dir][4] * fh + M[dir][5];
                float rz = M[dir][7] * fh + M[dir][8];
#pragma unroll
                for (int k = 0; k < 4; k++) {
                    float fw = (float)(w4 * 4 + k);
                    float d  = dst[dir][k];
                    float px = d * (M[dir][0] * fw + rx) + kt[dir][0];
                    float py = d * (M[dir][3] * fw + ry) + kt[dir][1];
                    float pz = d * (M[dir][6] * fw + rz) + kt[dir][2];
                    float scale = (fabsf(pz) > EPSV) ? (1.0f / pz) : 1.0f;
                    float ix = px * scale, iy = py * scale;
                    float x0f = floorf(ix), y0f = floorf(iy);
                    float wx1 = ix - x0f, wy1 = iy - y0f;
                    float wx0 = 1.0f - wx1, wy0 = 1.0f - wy1;
                    // validity on UNclamped tap coords (reference zero-pad)
                    bool vx0 = (x0f >= 0.0f)        & (x0f <= (float)(W - 1));
                    bool vx1 = (x0f + 1.0f >= 0.0f) & (x0f + 1.0f <= (float)(W - 1));
                    bool vy0 = (y0f >= 0.0f)        & (y0f <= (float)(H - 1));
                    bool vy1 = (y0f + 1.0f >= 0.0f) & (y0f + 1.0f <= (float)(H - 1));
                    float mxl = vx0 ? wx0 : 0.0f;
                    float mxr = vx1 ? wx1 : 0.0f;
                    float myt = vy0 ? wy0 : 0.0f;
                    float myb = vy1 ? wy1 : 0.0f;
                    // column fold (proven in R4): pair base xp, 0/1 selects
                    int xi0 = (int)fminf(fmaxf(x0f,        0.0f), (float)(W - 1));
                    int xi1 = (int)fminf(fmaxf(x0f + 1.0f, 0.0f), (float)(W - 1));
                    int xp  = min(xi0, W - 2);
                    int sL = xi0 - xp, sR = xi1 - xp;
                    cax[dir][k] = (sL ? 0.0f : mxl) + (sR ? 0.0f : mxr);  // col xp
                    cbx[dir][k] = (sL ? mxl : 0.0f) + (sR ? mxr : 0.0f);  // col xp+1
                    // row fold: packed lo-slot = row yload, hi-slot = row yload+1.
                    // If y0<0 the valid row (y1=0) sits in the lo-slot -> swap.
                    int  yload  = (int)fminf(fmaxf(y0f, 0.0f), (float)(H - 1));
                    bool rowswp = (y0f < 0.0f);
                    cra[dir][k] = rowswp ? myb : myt;    // weight on lo-slot
                    crb[dir][k] = rowswp ? 0.0f : myb;   // weight on hi-slot
                    pv[dir][k] = load8u(pk[dir] + yload * W + xp);
                }
            }
            // 8 quad-tap loads in flight; no sinking past this point.
            __builtin_amdgcn_sched_barrier(0);
#pragma unroll
            for (int dir = 0; dir < 2; dir++)
#pragma unroll
                for (int k = 0; k < 4; k++) {
                    float2 f0 = h2f2(pv[dir][k].x);   // col xp:   (rowY, rowY+1)
                    float2 f1 = h2f2(pv[dir][k].y);   // col xp+1: (rowY, rowY+1)
                    float g = cra[dir][k] * (cax[dir][k] * f0.x + cbx[dir][k] * f1.x)
                            + crb[dir][k] * (cax[dir][k] * f0.y + cbx[dir][k] * f1.y);
                    sum += fabsf(g - dst[dir][k]);
                }
        }
    }

#pragma unroll
    for (int off2 = 32; off2 > 0; off2 >>= 1) sum += __shfl_down(sum, off2, 64);
    __shared__ float smem[NTHREADS / 64];
    int lane = threadIdx.x & 63, wid = threadIdx.x >> 6;
    if (lane == 0) smem[wid] = sum;
    __syncthreads();
    if (threadIdx.x == 0) {
        float t = 0.0f;
#pragma unroll
        for (int i = 0; i < NTHREADS / 64; i++) t += smem[i];
        partials[blockIdx.x] = t;
    }
}

// ---- Fallback (proven R4, 117 us): used only if ws_size < WS_NEEDED ----
__device__ inline float2 load2u(const float* __restrict__ p) {
    float2 v;
    __builtin_memcpy(&v, p, sizeof(float2));
    return v;
}

__global__ __launch_bounds__(NTHREADS, 4) void grl_warp_loss_fallback(
        const float* __restrict__ cur, const float* __restrict__ nxt,
        const float* __restrict__ ws, float* __restrict__ partials) {
    int bid = blockIdx.x;
    int xcd = bid & (NXCD - 1);
    int j   = bid >> 3;
    int tid0 = j * NTHREADS + (int)threadIdx.x;
    float sum = 0.0f;

    for (int bb = 0; bb < 2; ++bb) {
        int b = xcd * 2 + bb;
        const float* __restrict__ prm = ws + b * 24;
        float M[2][9], kt[2][3];
#pragma unroll
        for (int i = 0; i < 9; i++) { M[0][i] = prm[i]; M[1][i] = prm[12 + i]; }
#pragma unroll
        for (int i = 0; i < 3; i++) { kt[0][i] = prm[9 + i]; kt[1][i] = prm[21 + i]; }
        const float* __restrict__ srcimg[2];
        srcimg[0] = cur + b * HW;
        srcimg[1] = nxt + b * HW;

        for (int idx = tid0; idx < HW4; idx += THR_PER_XCD) {
            int h  = idx / W4;
            int w4 = idx - h * W4;
            int p  = idx * 4;
            const float4 c4 = *(const float4*)(srcimg[0] + p);
            const float4 n4 = *(const float4*)(srcimg[1] + p);
            float fh = (float)h;
            float dst[2][4] = { { n4.x, n4.y, n4.z, n4.w },
                                { c4.x, c4.y, c4.z, c4.w } };
            float2 pv0[2][4], pv1[2][4];
            float  c00[2][4], c01[2][4], c10[2][4], c11[2][4];
#pragma unroll
            for (int dir = 0; dir < 2; dir++) {
                float rx = M[dir][1] * fh + M[dir][2];
                float ry = M[dir][4] * fh + M[dir][5];
                float rz = M[dir][7] * fh + M[dir][8];
#pragma unroll
                for (int k = 0; k < 4; k++) {
                    float fw = (float)(w4 * 4 + k);
                    float d  = dst[dir][k];
                    float px = d * (M[dir][0] * fw + rx) + kt[dir][0];
                    float py = d * (M[dir][3] * fw + ry) + kt[dir][1];
                    float pz = d * (M[dir][6] * fw + rz) + kt[dir][2];
                    float scale = (fabsf(pz) > EPSV) ? (1.0f / pz) : 1.0f;
                    float ix = px * scale, iy = py * scale;
                    float x0f = floorf(ix), y0f = floorf(iy);
                    float wx1 = ix - x0f, wy1 = iy - y0f;
                    float wx0 = 1.0f - wx1, wy0 = 1.0f - wy1;
                    bool vx0 = (x0f >= 0.0f)        & (x0f <= (float)(W - 1));
                    bool vx1 = (x0f + 1.0f >= 0.0f) & (x0f + 1.0f <= (float)(W - 1));
                    bool vy0 = (y0f >= 0.0f)        & (y0f <= (float)(H - 1));
                    bool vy1 = (y0f + 1.0f >= 0.0f) & (y0f + 1.0f <= (float)(H - 1));
                    float mxl = vx0 ? wx0 : 0.0f;
                    float mxr = vx1 ? wx1 : 0.0f;
                    float myt = vy0 ? wy0 : 0.0f;
                    float myb = vy1 ? wy1 : 0.0f;
                    int xi0 = (int)fminf(fmaxf(x0f,        0.0f), (float)(W - 1));
                    int xi1 = (int)fminf(fmaxf(x0f + 1.0f, 0.0f), (float)(W - 1));
                    int yi0 = (int)fminf(fmaxf(y0f,        0.0f), (float)(H - 1));
                    int yi1 = (int)fminf(fmaxf(y0f + 1.0f, 0.0f), (float)(H - 1));
                    int xp  = min(xi0, W - 2);
                    int sL = xi0 - xp, sR = xi1 - xp;
                    float ax = (sL ? 0.0f : mxl) + (sR ? 0.0f : mxr);
                    float bx = (sL ? mxl : 0.0f) + (sR ? mxr : 0.0f);
                    c00[dir][k] = ax * myt;
                    c01[dir][k] = bx * myt;
                    c10[dir][k] = ax * myb;
                    c11[dir][k] = bx * myb;
                    pv0[dir][k] = load2u(srcimg[dir] + yi0 * W + xp);
                    pv1[dir][k] = load2u(srcimg[dir] + yi1 * W + xp);
                }
            }
            __builtin_amdgcn_sched_barrier(0);
#pragma unroll
            for (int dir = 0; dir < 2; dir++)
#pragma unroll
                for (int k = 0; k < 4; k++) {
                    float g = pv0[dir][k].x * c00[dir][k] + pv0[dir][k].y * c01[dir][k]
                            + pv1[dir][k].x * c10[dir][k] + pv1[dir][k].y * c11[dir][k];
                    sum += fabsf(g - dst[dir][k]);
                }
        }
    }

#pragma unroll
    for (int off2 = 32; off2 > 0; off2 >>= 1) sum += __shfl_down(sum, off2, 64);
    __shared__ float smem[NTHREADS / 64];
    int lane = threadIdx.x & 63, wid = threadIdx.x >> 6;
    if (lane == 0) smem[wid] = sum;
    __syncthreads();
    if (threadIdx.x == 0) {
        float t = 0.0f;
#pragma unroll
        for (int i = 0; i < NTHREADS / 64; i++) t += smem[i];
        partials[blockIdx.x] = t;
    }
}

__global__ __launch_bounds__(256) void grl_finalize_kernel(const float* __restrict__ partials,
                                                           float* __restrict__ out) {
    float sum = 0.0f;
    for (int i = threadIdx.x; i < NBLOCKS; i += 256) sum += partials[i];
#pragma unroll
    for (int off = 32; off > 0; off >>= 1) sum += __shfl_down(sum, off, 64);
    __shared__ float smem[4];
    int lane = threadIdx.x & 63, wid = threadIdx.x >> 6;
    if (lane == 0) smem[wid] = sum;
    __syncthreads();
    if (threadIdx.x == 0) {
        float t = smem[0] + smem[1] + smem[2] + smem[3];
        out[0] = t * (0.1f / (2.0f * (float)NPIX));
    }
}

extern "C" void kernel_launch(void* const* d_in, const int* in_sizes, int n_in,
                              void* d_out, int out_size, void* d_ws, size_t ws_size,
                              hipStream_t stream) {
    const float* cur  = (const float*)d_in[0];
    const float* nxt  = (const float*)d_in[1];
    const float* cpos = (const float*)d_in[2];
    const float* npos = (const float*)d_in[3];
    const float* cang = (const float*)d_in[4];
    const float* nang = (const float*)d_in[5];
    const float* Kmat = (const float*)d_in[6];
    float* ws = (float*)d_ws;
    float* partials = ws + PARAMS_FLOATS;

    grl_setup_kernel<<<1, 64, 0, stream>>>(cpos, npos, cang, nang, Kmat, ws);
    if (ws_size >= WS_NEEDED) {
        unsigned int* packed = (unsigned int*)(ws + PACK_OFF_FLOATS);
        grl_pack_kernel<<<PK_BLOCKS, NTHREADS, 0, stream>>>(cur, nxt, packed);
        grl_warp_loss_packed<<<NBLOCKS, NTHREADS, 0, stream>>>(cur, nxt, packed, ws, partials);
    } else {
        grl_warp_loss_fallback<<<NBLOCKS, NTHREADS, 0, stream>>>(cur, nxt, ws, partials);
    }
    grl_finalize_kernel<<<1, 256, 0, stream>>>(partials, (float*)d_out);
}